// Round 15
// baseline (440.541 us; speedup 1.0000x reference)
//
#include <hip/hip_runtime.h>

#define B_    8
#define N1_   16384
#define N2_   4096
#define NTOT_ (B_ * N1_)

// ---------------------------------------------------------------------------
// GOLD SEMANTICS (verified R12-R14, absmax 0.015625 = bf16 output floor):
//   s  = ((x*x + y*y) + z*z)          plain forward, no fma
//   dot= fma(x,x', fma(y,y', z*z'))   z-first FMA chain (numpy AVX2 einsum)
//   d2 = fma(-2, dot, s1+s2)          bitwise == plain (s1+s2) - 2*dot
//   w  : r = 1/(d2+1e-8), w = r/((r0+r1)+r2), plain f32
// R14 post-mortem: GEMM staging tweaks were NEUTRAL; rest-time is gather
// L2-thrash (16MB f_t vs per-XCD 4MB L2) + phase1 insert overhead (22.7
// VALU inst/candidate, ~13 on branchy insert). R15: branchless insert,
// XCD-affinity gather swizzle (batch == blockIdx&7), merge fused into
// gather, preps fused. Selection arithmetic untouched.
// ---------------------------------------------------------------------------
__device__ __forceinline__ float np_sumsq(float x, float y, float z)
{
#pragma clang fp contract(off)
    return ((x * x + y * y) + z * z);   // forward, plain (no contraction)
}

// ---------------------------------------------------------------------------
// fused prep: blocks [0,128) fold0 | [128,192) fold1 | [192,320) q4
// ---------------------------------------------------------------------------
__global__ __launch_bounds__(256) void prep_kernel(
    const float* __restrict__ p2,
    const float* __restrict__ W0, const float* __restrict__ b0,
    const float* __restrict__ g0, const float* __restrict__ be0,
    const float* __restrict__ m0, const float* __restrict__ v0,
    const float* __restrict__ W1, const float* __restrict__ b1,
    const float* __restrict__ g1, const float* __restrict__ be1,
    const float* __restrict__ m1, const float* __restrict__ v1,
    float* __restrict__ W0p, float* __restrict__ b0p,
    float* __restrict__ W1p, float* __restrict__ b1p,
    float4* __restrict__ q4)
{
    const int blk = blockIdx.x, tid = threadIdx.x;
    if (blk < 128) {                       // fold0: 128x256 weights
        const int t = blk * 256 + tid;     // < 32768
        const int o = t >> 8;
        const float s = g0[o] / sqrtf(v0[o] + 1e-5f);
        W0p[t] = W0[t] * s;
        if (t < 128) {
            const float sb = g0[t] / sqrtf(v0[t] + 1e-5f);
            b0p[t] = be0[t] + (b0[t] - m0[t]) * sb;
        }
    } else if (blk < 192) {                // fold1: 128x128 weights
        const int t = (blk - 128) * 256 + tid;  // < 16384
        const int o = t >> 7;
        const float s = g1[o] / sqrtf(v1[o] + 1e-5f);
        W1p[t] = W1[t] * s;
        if (t < 128) {
            const float sb = g1[t] / sqrtf(v1[t] + 1e-5f);
            b1p[t] = be1[t] + (b1[t] - m1[t]) * sb;
        }
    } else {                               // q4 pack: 32768 points
        const int t = (blk - 192) * 256 + tid;
        const float x = p2[3 * (size_t)t + 0];
        const float y = p2[3 * (size_t)t + 1];
        const float z = p2[3 * (size_t)t + 2];
        q4[t] = make_float4(x, y, z, np_sumsq(x, y, z));
    }
}

// ---------------------------------------------------------------------------
// f32 tiled GEMM + bias + ReLU (128x128 tile, 8x8/thread, float4 staging).
// TRANS=false: Y [B][128][N2]; TRANS=true: Y [B][N2][128] via LDS transpose.
// ---------------------------------------------------------------------------
template <int CIN, bool TRANS>
__global__ __launch_bounds__(256) void gemm_relu_kernel(
    const float* __restrict__ X, const float* __restrict__ Wp,
    const float* __restrict__ bp, float* __restrict__ Y)
{
    __shared__ float A_lds[32][136];
    __shared__ float B_lds[32][128];

    const int b  = blockIdx.y;
    const int n0 = blockIdx.x * 128;
    const int tid = threadIdx.x;
    const int ty = tid >> 4;
    const int tx = tid & 15;
    const float* Xb = X + (size_t)b * CIN * N2_;

    float acc[8][8];
#pragma unroll
    for (int i = 0; i < 8; ++i)
#pragma unroll
        for (int j = 0; j < 8; ++j) acc[i][j] = 0.f;

    const int a_kq = (tid & 7) * 4;
    const int a_r0 = tid >> 3;
    const int b_n4 = (tid & 31) * 4;
    const int b_k0 = tid >> 5;

    for (int k0 = 0; k0 < CIN; k0 += 32) {
#pragma unroll
        for (int i = 0; i < 4; ++i) {
            const int row = a_r0 + 32 * i;
            const float4 v = *(const float4*)&Wp[(size_t)row * CIN + k0 + a_kq];
            A_lds[a_kq + 0][row] = v.x;
            A_lds[a_kq + 1][row] = v.y;
            A_lds[a_kq + 2][row] = v.z;
            A_lds[a_kq + 3][row] = v.w;
        }
#pragma unroll
        for (int i = 0; i < 4; ++i) {
            const int krow = b_k0 + 8 * i;
            *(float4*)&B_lds[krow][b_n4] =
                *(const float4*)&Xb[(size_t)(k0 + krow) * N2_ + n0 + b_n4];
        }
        __syncthreads();

#pragma unroll
        for (int kk = 0; kk < 32; ++kk) {
            const float4 a0 = *(const float4*)&A_lds[kk][ty * 4];
            const float4 a1 = *(const float4*)&A_lds[kk][64 + ty * 4];
            const float4 bq0 = *(const float4*)&B_lds[kk][tx * 4];
            const float4 bq1 = *(const float4*)&B_lds[kk][64 + tx * 4];
            const float av[8] = {a0.x, a0.y, a0.z, a0.w, a1.x, a1.y, a1.z, a1.w};
            const float bv[8] = {bq0.x, bq0.y, bq0.z, bq0.w, bq1.x, bq1.y, bq1.z, bq1.w};
#pragma unroll
            for (int i = 0; i < 8; ++i)
#pragma unroll
                for (int j = 0; j < 8; ++j)
                    acc[i][j] = fmaf(av[i], bv[j], acc[i][j]);
        }
        __syncthreads();
    }

    float bias_v[8];
#pragma unroll
    for (int i = 0; i < 8; ++i) {
        const int r = (i < 4) ? (ty * 4 + i) : (64 + ty * 4 + (i - 4));
        bias_v[i] = bp[r];
    }

    if (!TRANS) {
#pragma unroll
        for (int i = 0; i < 8; ++i) {
            const int r = (i < 4) ? (ty * 4 + i) : (64 + ty * 4 + (i - 4));
            float* yrow = Y + ((size_t)b * 128 + r) * N2_ + n0;
            float4 v0, v1;
            v0.x = fmaxf(acc[i][0] + bias_v[i], 0.f);
            v0.y = fmaxf(acc[i][1] + bias_v[i], 0.f);
            v0.z = fmaxf(acc[i][2] + bias_v[i], 0.f);
            v0.w = fmaxf(acc[i][3] + bias_v[i], 0.f);
            v1.x = fmaxf(acc[i][4] + bias_v[i], 0.f);
            v1.y = fmaxf(acc[i][5] + bias_v[i], 0.f);
            v1.z = fmaxf(acc[i][6] + bias_v[i], 0.f);
            v1.w = fmaxf(acc[i][7] + bias_v[i], 0.f);
            *(float4*)(yrow + tx * 4) = v0;
            *(float4*)(yrow + 64 + tx * 4) = v1;
        }
    } else {
        float (*T)[132] = (float(*)[132])&A_lds[0][0];
#pragma unroll
        for (int s = 0; s < 4; ++s) {
            if ((tx >> 3) == (s & 1)) {
                const int joff = (s >> 1) * 4;
                const int cl0 = (tx & 7) * 4;
#pragma unroll
                for (int i = 0; i < 8; ++i) {
                    const int r = (i < 4) ? (ty * 4 + i) : (64 + ty * 4 + (i - 4));
#pragma unroll
                    for (int j = 0; j < 4; ++j)
                        T[cl0 + j][r] = fmaxf(acc[i][j + joff] + bias_v[i], 0.f);
                }
            }
            __syncthreads();
#pragma unroll
            for (int p = 0; p < 4; ++p) {
                const int row = (tid >> 5) + 8 * p;
                const float4 v = *(const float4*)&T[row][(tid & 31) * 4];
                float* orow = Y + ((size_t)b * N2_ + n0 + 32 * s + row) * 128;
                *(float4*)&orow[(tid & 31) * 4] = v;
            }
            __syncthreads();
        }
    }
}

// ---------------------------------------------------------------------------
// KNN phase 1: block = 256 queries x 1 chunk of 1024 candidates; gold-d2
// scan key; BRANCHLESS top-3 (3 cmp + 10 cndmask, == strict-< insert incl.
// tie stability). Partials out, chunk-major layout.
// ---------------------------------------------------------------------------
__global__ __launch_bounds__(256, 8) void knn_phase1(
    const float* __restrict__ p1, const float4* __restrict__ q4,
    float* __restrict__ part_d, int* __restrict__ part_i)
{
    __shared__ float4 qs[1024];           // 16 KB
    const int tid = threadIdx.x;
    const int chunk = blockIdx.x & 3;
    const int g = (blockIdx.x >> 2) * 256 + tid;
    const int b = g >> 14;

    const float px = p1[3 * (size_t)g + 0];
    const float py = p1[3 * (size_t)g + 1];
    const float pz = p1[3 * (size_t)g + 2];
    const float s1 = np_sumsq(px, py, pz);

    const float4* qb = q4 + (size_t)b * N2_ + chunk * 1024;
#pragma unroll
    for (int i = 0; i < 4; ++i) qs[tid + i * 256] = qb[tid + i * 256];
    __syncthreads();

    float d0 = 1e30f, d1 = 1e30f, d2v = 1e30f;
    int i0 = 0, i1 = 0, i2 = 0;
    const int jbase = chunk * 1024;

    for (int j = 0; j < 1024; j += 4) {
#pragma unroll
        for (int u = 0; u < 4; ++u) {
            const float4 q = qs[j + u];
            const float dot = __fmaf_rn(px, q.x, __fmaf_rn(py, q.y, __fmul_rn(pz, q.z)));
            const float ss  = s1 + q.w;
            const float t   = __fmaf_rn(-2.0f, dot, ss);
            const int jj = jbase + j + u;
            // branchless stable top-3 (== strict-< insert)
            const bool c0 = t < d0, c1 = t < d1, c2 = t < d2v;
            const float nd2 = c1 ? d1 : (c2 ? t : d2v);
            const int   ni2 = c1 ? i1 : (c2 ? jj : i2);
            const float nd1 = c0 ? d0 : (c1 ? t : d1);
            const int   ni1 = c0 ? i0 : (c1 ? jj : i1);
            d0 = c0 ? t : d0;  i0 = c0 ? jj : i0;
            d1 = nd1;          i1 = ni1;
            d2v = nd2;         i2 = ni2;
        }
    }

    part_d[(0 * 4 + chunk) * NTOT_ + g] = d0;
    part_d[(1 * 4 + chunk) * NTOT_ + g] = d1;
    part_d[(2 * 4 + chunk) * NTOT_ + g] = d2v;
    part_i[(0 * 4 + chunk) * NTOT_ + g] = i0;
    part_i[(1 * 4 + chunk) * NTOT_ + g] = i1;
    part_i[(2 * 4 + chunk) * NTOT_ + g] = i2;
}

// ---------------------------------------------------------------------------
// gather + fused merge.  Block = 64 points x 4 channel-groups, with
// XCD-affinity swizzle: batch == blockIdx&7 so each XCD's L2 only caches
// its own batch's 2MB f_t slice (fits 4MB L2).  Threads 0..63 first do the
// stable 12-way merge (chunk-major == R13/R14 order) + gold weights -> LDS.
// ---------------------------------------------------------------------------
__global__ __launch_bounds__(256) void gather_merge_kernel(
    const float* __restrict__ f_t, const float* __restrict__ part_d,
    const int* __restrict__ part_i, float* __restrict__ out)
{
    __shared__ float wL[3][64];
    __shared__ int   iL[3][64];

    const int tid = threadIdx.x;
    // swizzle: old linear block = (sb>>3) + (sb&7)*256 ; batch = sb&7
    const int oldb = (blockIdx.x >> 3) + (blockIdx.x & 7) * 256;

    if (tid < 64) {
        const int g = oldb * 64 + tid;
        float d0 = 1e30f, d1 = 1e30f, d2v = 1e30f;
        int i0 = 0, i1 = 0, i2 = 0;
#pragma unroll
        for (int c = 0; c < 4; ++c) {          // chunk-major: stable tie order
#pragma unroll
            for (int k = 0; k < 3; ++k) {
                const float t = part_d[(k * 4 + c) * NTOT_ + g];
                const int  jj = part_i[(k * 4 + c) * NTOT_ + g];
                if (t < d2v) {
                    const bool c1 = t < d1, c0 = t < d0;
                    d2v = c1 ? d1 : t;                 i2 = c1 ? i1 : jj;
                    const float nd1 = c1 ? (c0 ? d0 : t) : d1;
                    const int   ni1 = c1 ? (c0 ? i0 : jj) : i1;
                    d1 = nd1;                          i1 = ni1;
                    d0 = c0 ? t : d0;                  i0 = c0 ? jj : i0;
                }
            }
        }
        float w0, w1, w2;
        {
#pragma clang fp contract(off)
            const float r0 = 1.0f / (d0 + 1e-8f);
            const float r1 = 1.0f / (d1 + 1e-8f);
            const float r2 = 1.0f / (d2v + 1e-8f);
            const float rs = (r0 + r1) + r2;
            w0 = r0 / rs;
            w1 = r1 / rs;
            w2 = r2 / rs;
        }
        wL[0][tid] = w0; wL[1][tid] = w1; wL[2][tid] = w2;
        iL[0][tid] = i0; iL[1][tid] = i1; iL[2][tid] = i2;
    }
    __syncthreads();

    const int lane = tid & 63, cg = tid >> 6;
    const int g = oldb * 64 + lane;
    const int b = g >> 14, n = g & 16383;

    const int i0 = iL[0][lane], i1 = iL[1][lane], i2 = iL[2][lane];
    const float w0 = wL[0][lane], w1 = wL[1][lane], w2 = wL[2][lane];

    const float* base = f_t + (size_t)b * N2_ * 128 + cg * 32;
    const float4* r0 = (const float4*)(base + (size_t)i0 * 128);
    const float4* r1 = (const float4*)(base + (size_t)i1 * 128);
    const float4* r2 = (const float4*)(base + (size_t)i2 * 128);

    float acc[32];
#pragma unroll
    for (int q = 0; q < 8; ++q) {
        const float4 a = r0[q], bb = r1[q], c = r2[q];
        acc[4 * q + 0] = fmaf(w0, a.x, fmaf(w1, bb.x, w2 * c.x));
        acc[4 * q + 1] = fmaf(w0, a.y, fmaf(w1, bb.y, w2 * c.y));
        acc[4 * q + 2] = fmaf(w0, a.z, fmaf(w1, bb.z, w2 * c.z));
        acc[4 * q + 3] = fmaf(w0, a.w, fmaf(w1, bb.w, w2 * c.w));
    }

    float* ob = out + ((size_t)b * 128 + cg * 32) * N1_ + n;
#pragma unroll
    for (int c = 0; c < 32; ++c)
        __builtin_nontemporal_store(acc[c], ob + (size_t)c * N1_);
}

// ---------------------------------------------------------------------------
extern "C" void kernel_launch(void* const* d_in, const int* in_sizes, int n_in,
                              void* d_out, int out_size, void* d_ws, size_t ws_size,
                              hipStream_t stream)
{
    const float* p1  = (const float*)d_in[0];
    const float* p2  = (const float*)d_in[1];
    const float* f2  = (const float*)d_in[2];
    const float* W0  = (const float*)d_in[3];
    const float* b0  = (const float*)d_in[4];
    const float* g0  = (const float*)d_in[5];
    const float* be0 = (const float*)d_in[6];
    const float* m0  = (const float*)d_in[7];
    const float* v0  = (const float*)d_in[8];
    const float* W1  = (const float*)d_in[9];
    const float* b1  = (const float*)d_in[10];
    const float* g1  = (const float*)d_in[11];
    const float* be1 = (const float*)d_in[12];
    const float* m1  = (const float*)d_in[13];
    const float* v1  = (const float*)d_in[14];

    char* ws = (char*)d_ws;
    float4* q4  = (float4*)(ws);                         // 512 KB
    float*  W0p = (float*)(ws + (512 << 10));            // 128 KB
    float*  b0p = (float*)(ws + (640 << 10));            // .5 KB
    float*  W1p = (float*)(ws + (644 << 10));            // 64 KB
    float*  b1p = (float*)(ws + (708 << 10));            // .5 KB
    float*  h   = (float*)(ws + ((size_t)1 << 20));      // 16 MB [B][128][N2] (dead after gemm2)
    float*  f_t = (float*)(ws + ((size_t)17 << 20));     // 16 MB [B][N2][128]
    // KNN partials reuse h's region (dead once gemm2 has run):
    float*  pd  = (float*)(ws + ((size_t)1 << 20));      // 6.29 MB
    int*    pi  = (int*)  (ws + ((size_t)9 << 20));      // 6.29 MB

    prep_kernel<<<320, 256, 0, stream>>>(p2,
        W0, b0, g0, be0, m0, v0, W1, b1, g1, be1, m1, v1,
        W0p, b0p, W1p, b1p, q4);

    gemm_relu_kernel<256, false><<<dim3(32, 8), 256, 0, stream>>>(f2, W0p, b0p, h);
    gemm_relu_kernel<128, true ><<<dim3(32, 8), 256, 0, stream>>>(h, W1p, b1p, f_t);

    knn_phase1<<<(NTOT_ / 256) * 4, 256, 0, stream>>>(p1, q4, pd, pi);
    gather_merge_kernel<<<NTOT_ / 64, 256, 0, stream>>>(f_t, pd, pi, (float*)d_out);
}